// Round 5
// baseline (3121.109 us; speedup 1.0000x reference)
//
#include <hip/hip_runtime.h>
#include <cstddef>

#define BB 4
#define TT 1024
#define DMODEL 512
#define DFF 2048
#define NHEAD 8
#define HDIM 64
#define NTOK (BB*TT)
#define NLAYER 6
#define MFOUT 256
#define LDK 40   // gemm LDS row stride (shorts) for BK=32

typedef __attribute__((ext_vector_type(8))) _Float16 f16x8;
typedef __attribute__((ext_vector_type(8))) short bf16x8;
typedef __attribute__((ext_vector_type(4))) float f32x4;
#define MFMAH(a,b,c) __builtin_amdgcn_mfma_f32_16x16x32_f16(a,b,c,0,0,0)
#define MFMAB(a,b,c) __builtin_amdgcn_mfma_f32_16x16x32_bf16(a,b,c,0,0,0)

union F16U { _Float16 h; unsigned short u; };

__device__ __forceinline__ unsigned f2bf(float f) {
    union { float f; unsigned u; } v; v.f = f;
    return (v.u + 0x7FFFu + ((v.u >> 16) & 1u)) >> 16;
}
__device__ __forceinline__ float bf2f(unsigned h) {
    union { unsigned u; float f; } v; v.u = h << 16;
    return v.f;
}
__device__ __forceinline__ unsigned short f16u(float v) {
    F16U t; t.h = (_Float16)v; return t.u;
}

// out modes for gemm_u
#define MODE_F32  0   // fp32 out (+optional res)
#define MODE_BF   1   // bf16 hi/lo pair
#define MODE_F16K 2   // f16 single
#define MODE_F16Q 3   // f16 hi + f16 mid*1024
#define MODE_F16V 4   // f16 hi + f16 lo

// ---------------- unified MFMA GEMM, bf16 hi/lo 3-pass ----------------
// A: bf16 pair (Ah/Al) if Ah!=null, else fp32 (Af, optional concat Af2 at col K1).
// W: fp32 [k][n], converted+transposed in-kernel. Tile 128x64, 4 waves, BK=32.
__global__ __launch_bounds__(256, 4)
void gemm_u(const unsigned short* __restrict__ Ah, const unsigned short* __restrict__ Al,
            const float* __restrict__ Af, const float* __restrict__ Af2, int K1, int lda, int lda2,
            const float* __restrict__ W, const float* __restrict__ bias,
            const float* __restrict__ alpha, const float* __restrict__ res,
            float* __restrict__ outf, unsigned short* __restrict__ o1,
            unsigned short* __restrict__ o2, int N, int K, int mode)
{
    __shared__ __align__(16) unsigned short Ahs[128*LDK];
    __shared__ __align__(16) unsigned short Als[128*LDK];
    __shared__ __align__(16) unsigned short Whs[64*LDK];
    __shared__ __align__(16) unsigned short Wls[64*LDK];
    const int tid = threadIdx.x;
    const int lane = tid & 63;
    const int w = tid >> 6;
    const int wm = w >> 1, wn = w & 1;
    const int quad = lane >> 4, c = lane & 15;
    const int m0 = blockIdx.y * 128;
    const int n0 = blockIdx.x * 64;

    f32x4 acc[4][2];
    #pragma unroll
    for (int mi = 0; mi < 4; mi++)
        #pragma unroll
        for (int ni = 0; ni < 2; ni++) { acc[mi][ni][0]=0.f; acc[mi][ni][1]=0.f; acc[mi][ni][2]=0.f; acc[mi][ni][3]=0.f; }

    for (int k0 = 0; k0 < K; k0 += 32) {
        if (Ah != nullptr) {
            // bf16-pair A: pure vector copies
            #pragma unroll
            for (int i = 0; i < 2; i++) {
                const int idx = tid + i * 256;
                const int r = idx >> 2, c8 = (idx & 3) * 8;
                *(uint4*)&Ahs[r * LDK + c8] = *(const uint4*)&Ah[(size_t)(m0 + r) * K + k0 + c8];
                *(uint4*)&Als[r * LDK + c8] = *(const uint4*)&Al[(size_t)(m0 + r) * K + k0 + c8];
            }
        } else {
            // fp32 A (+concat), convert in-kernel
            #pragma unroll
            for (int i = 0; i < 4; i++) {
                const int idx = tid + i * 256;
                const int r = idx >> 3, c4 = (idx & 7) * 4;
                const int gk = k0 + c4;
                const float* src = (Af2 != nullptr && gk >= K1)
                                 ? &Af2[(size_t)(m0 + r) * lda2 + (gk - K1)]
                                 : &Af [(size_t)(m0 + r) * lda  + gk];
                const float4 v = *(const float4*)src;
                const unsigned h0 = f2bf(v.x), h1 = f2bf(v.y), h2 = f2bf(v.z), h3 = f2bf(v.w);
                *(uint2*)&Ahs[r * LDK + c4] = make_uint2(h0 | (h1 << 16), h2 | (h3 << 16));
                const unsigned l0 = f2bf(v.x - bf2f(h0)), l1 = f2bf(v.y - bf2f(h1));
                const unsigned l2 = f2bf(v.z - bf2f(h2)), l3 = f2bf(v.w - bf2f(h3));
                *(uint2*)&Als[r * LDK + c4] = make_uint2(l0 | (l1 << 16), l2 | (l3 << 16));
            }
        }
        // W tile 32x64 -> hi/lo transposed [n][k]
        #pragma unroll
        for (int i = 0; i < 2; i++) {
            const int idx = tid + i * 256;
            const int r = idx >> 4, c4 = (idx & 15) * 4;
            const float4 v = *(const float4*)&W[(size_t)(k0 + r) * N + n0 + c4];
            const float va[4] = {v.x, v.y, v.z, v.w};
            #pragma unroll
            for (int j = 0; j < 4; j++) {
                const unsigned h = f2bf(va[j]);
                Whs[(c4 + j) * LDK + r] = (unsigned short)h;
                Wls[(c4 + j) * LDK + r] = (unsigned short)f2bf(va[j] - bf2f(h));
            }
        }
        __syncthreads();
        bf16x8 ah[4], al2[4], bh[2], bl2[2];
        #pragma unroll
        for (int mi = 0; mi < 4; mi++) {
            const int row = (wm * 64 + mi * 16 + c) * LDK + quad * 8;
            ah[mi]  = *(const bf16x8*)&Ahs[row];
            al2[mi] = *(const bf16x8*)&Als[row];
        }
        #pragma unroll
        for (int ni = 0; ni < 2; ni++) {
            const int row = (wn * 32 + ni * 16 + c) * LDK + quad * 8;
            bh[ni]  = *(const bf16x8*)&Whs[row];
            bl2[ni] = *(const bf16x8*)&Wls[row];
        }
        #pragma unroll
        for (int mi = 0; mi < 4; mi++)
            #pragma unroll
            for (int ni = 0; ni < 2; ni++) {
                acc[mi][ni] = MFMAB(ah[mi],  bh[ni],  acc[mi][ni]);
                acc[mi][ni] = MFMAB(al2[mi], bh[ni],  acc[mi][ni]);
                acc[mi][ni] = MFMAB(ah[mi],  bl2[ni], acc[mi][ni]);
            }
        __syncthreads();
    }
    const float alv = alpha ? alpha[0] : 0.f;
    #pragma unroll
    for (int mi = 0; mi < 4; mi++)
        #pragma unroll
        for (int ni = 0; ni < 2; ni++) {
            const int gn = n0 + wn * 32 + ni * 16 + c;
            const float bv = bias ? bias[gn] : 0.f;
            #pragma unroll
            for (int r = 0; r < 4; r++) {
                const int gm = m0 + wm * 64 + mi * 16 + quad * 4 + r;
                const size_t oix = (size_t)gm * N + gn;
                float v = acc[mi][ni][r] + bv;
                if (alpha) v = (v >= 0.f) ? v : alv * v;
                if (mode == MODE_F32) {
                    if (res) v += res[oix];
                    outf[oix] = v;
                } else if (mode == MODE_BF) {
                    const unsigned h = f2bf(v);
                    o1[oix] = (unsigned short)h;
                    o2[oix] = (unsigned short)f2bf(v - bf2f(h));
                } else if (mode == MODE_F16K) {
                    o1[oix] = f16u(v);
                } else if (mode == MODE_F16Q) {
                    F16U t; t.h = (_Float16)v;
                    o1[oix] = t.u;
                    o2[oix] = f16u((v - (float)t.h) * 1024.f);
                } else { // MODE_F16V
                    F16U t; t.h = (_Float16)v;
                    o1[oix] = t.u;
                    o2[oix] = f16u(v - (float)t.h);
                }
            }
        }
}

// ---------------- LayerNorm: one wave per token -> bf16 hi/lo pair ----------------
__global__ __launch_bounds__(64)
void ln_kernel(const float* __restrict__ x, const float* __restrict__ g,
               const float* __restrict__ b, unsigned short* __restrict__ oh,
               unsigned short* __restrict__ ol)
{
    const int token = blockIdx.x;
    const int lane = threadIdx.x;
    const float* row = x + (size_t)token * DMODEL;
    float v[8];
    *(float4*)&v[0] = *(const float4*)&row[lane * 4];
    *(float4*)&v[4] = *(const float4*)&row[256 + lane * 4];
    float s = 0.f, s2 = 0.f;
    #pragma unroll
    for (int i = 0; i < 8; i++) { s += v[i]; s2 += v[i] * v[i]; }
    #pragma unroll
    for (int off = 1; off < 64; off <<= 1) {
        s  += __shfl_xor(s, off);
        s2 += __shfl_xor(s2, off);
    }
    const float mean = s * (1.f / DMODEL);
    const float var  = s2 * (1.f / DMODEL) - mean * mean;
    const float rstd = rsqrtf(var + 1e-5f);
    #pragma unroll
    for (int hh = 0; hh < 2; hh++) {
        const int base = hh * 256 + lane * 4;
        const float4 gv = *(const float4*)&g[base];
        const float4 bv = *(const float4*)&b[base];
        float o[4];
        o[0] = (v[hh*4+0] - mean) * rstd * gv.x + bv.x;
        o[1] = (v[hh*4+1] - mean) * rstd * gv.y + bv.y;
        o[2] = (v[hh*4+2] - mean) * rstd * gv.z + bv.z;
        o[3] = (v[hh*4+3] - mean) * rstd * gv.w + bv.w;
        ushort4 ph, pl;
        unsigned short* php = (unsigned short*)&ph;
        unsigned short* plp = (unsigned short*)&pl;
        #pragma unroll
        for (int j = 0; j < 4; j++) {
            const unsigned hb = f2bf(o[j]);
            php[j] = (unsigned short)hb;
            plp[j] = (unsigned short)f2bf(o[j] - bf2f(hb));
        }
        *(ushort4*)&oh[(size_t)token * DMODEL + base] = ph;
        *(ushort4*)&ol[(size_t)token * DMODEL + base] = pl;
    }
}

// ---------------- fp32 -> bf16 hi/lo pair (elementwise) ----------------
__global__ __launch_bounds__(256)
void cvt_pair(const float* __restrict__ x, unsigned short* __restrict__ oh,
              unsigned short* __restrict__ ol)
{
    const int idx = (blockIdx.x * 256 + threadIdx.x) * 4;
    const float4 v = *(const float4*)&x[idx];
    const float va[4] = {v.x, v.y, v.z, v.w};
    ushort4 ph, pl;
    unsigned short* php = (unsigned short*)&ph;
    unsigned short* plp = (unsigned short*)&pl;
    #pragma unroll
    for (int j = 0; j < 4; j++) {
        const unsigned hb = f2bf(va[j]);
        php[j] = (unsigned short)hb;
        plp[j] = (unsigned short)f2bf(va[j] - bf2f(hb));
    }
    *(ushort4*)&oh[idx] = ph;
    *(ushort4*)&ol[idx] = pl;
}

// ---------------- attention key-validity mask ----------------
__global__ __launch_bounds__(64)
void mask_kernel(const float* __restrict__ mask_in, float* __restrict__ mk)
{
    const int token = blockIdx.x;
    const int lane = threadIdx.x;
    const float* row = mask_in + (size_t)token * DMODEL;
    const float4 a = *(const float4*)&row[lane * 4];
    const float4 c = *(const float4*)&row[256 + lane * 4];
    float s = a.x + a.y + a.z + a.w + c.x + c.y + c.z + c.w;
    #pragma unroll
    for (int off = 1; off < 64; off <<= 1) s += __shfl_xor(s, off);
    if (lane == 0) mk[token] = (s > 0.f) ? 0.f : -1e9f;
}

// ---------------- relative position table E -> f16 hi/lo (2047, 64) ----------------
__global__ __launch_bounds__(64)
void e_kernel(const float* __restrict__ w1, const float* __restrict__ b1,
              const float* __restrict__ a1, const float* __restrict__ w2,
              const float* __restrict__ b2,
              unsigned short* __restrict__ Ehi, unsigned short* __restrict__ Elo)
{
    __shared__ float t1[DMODEL];
    const int r = blockIdx.x;
    const int lane = threadIdx.x;
    const float rel = (float)r - 1023.f;
    const float al = a1[0];
    for (int j = lane; j < DMODEL; j += 64) {
        float v = rel * w1[j] + b1[j];
        t1[j] = (v >= 0.f) ? v : al * v;
    }
    __syncthreads();
    float acc = b2[lane];
    for (int j = 0; j < DMODEL; j++)
        acc = fmaf(t1[j], w2[j * HDIM + lane], acc);
    F16U t; t.h = (_Float16)acc;
    Ehi[(size_t)r * HDIM + lane] = t.u;
    Elo[(size_t)r * HDIM + lane] = f16u(acc - (float)t.h);
}

// ---------------- keyframe encoder layer 1 (K=2) -> bf16 pair ----------------
__global__ __launch_bounds__(256)
void kf1_kernel(const float* __restrict__ p, const float* __restrict__ w1,
                const float* __restrict__ b1, const float* __restrict__ a1,
                unsigned short* __restrict__ oh, unsigned short* __restrict__ ol)
{
    const int idx = blockIdx.x * 256 + threadIdx.x;
    const int m = idx >> 9, n = idx & 511;
    float v = fmaf(p[m*2], w1[n], fmaf(p[m*2+1], w1[DMODEL + n], b1[n]));
    v = (v >= 0.f) ? v : a1[0] * v;
    const unsigned hb = f2bf(v);
    oh[idx] = (unsigned short)hb;
    ol[idx] = (unsigned short)f2bf(v - bf2f(hb));
}

// ---------------- MFMA flash attention, f16 hi/lo, pre-converted inputs ----------------
// Q/K/V arrive f16 (Q: hi+mid*1024, K: single, V: hi+lo). O out as bf16 pair.
__global__ __launch_bounds__(256, 2)
void attn_mfma(const _Float16* __restrict__ qhg, const _Float16* __restrict__ qmg,
               const _Float16* __restrict__ kg, const _Float16* __restrict__ vhg,
               const _Float16* __restrict__ vlg, const _Float16* __restrict__ Ehi,
               const _Float16* __restrict__ Elo, const float* __restrict__ mk,
               unsigned short* __restrict__ obh, unsigned short* __restrict__ obl)
{
    __shared__ __align__(16) _Float16 Ks [64*72];
    __shared__ __align__(16) _Float16 Vth[64*72];
    __shared__ __align__(16) _Float16 Vtl[64*72];
    __shared__ __align__(16) _Float16 Phs[64*72];
    __shared__ __align__(16) _Float16 Pls[64*72];

    const int tid = threadIdx.x;
    const int lane = tid & 63;
    const int w = tid >> 6;
    const int quad = lane >> 4;
    const int c = lane & 15;
    const int q0 = blockIdx.x * 64;
    const int hh = blockIdx.y;
    const int bb = blockIdx.z;
    const size_t base = (size_t)bb * TT * DMODEL + (size_t)hh * HDIM;
    const float* mkp = mk + bb * TT;

    // Q fragments: direct global loads (no LDS round-trip)
    f16x8 qh[2], qm[2];
    {
        const size_t qrow = base + (size_t)(q0 + 16 * w + c) * DMODEL;
        #pragma unroll
        for (int s = 0; s < 2; s++) {
            qh[s] = *(const f16x8*)&qhg[qrow + s * 32 + quad * 8];
            qm[s] = *(const f16x8*)&qmg[qrow + s * 32 + quad * 8];
        }
    }

    f32x4 O[4];
    #pragma unroll
    for (int dt = 0; dt < 4; dt++) { O[dt][0]=0.f; O[dt][1]=0.f; O[dt][2]=0.f; O[dt][3]=0.f; }
    float mrun[4] = {-1e30f, -1e30f, -1e30f, -1e30f};
    float lrun[4] = {0.f, 0.f, 0.f, 0.f};
    const int Jb = 48 - 16 * w;

    for (int kt = 0; kt < 16; kt++) {
        const int k0 = kt * 64;
        const size_t kvbase = base + (size_t)k0 * DMODEL;
        const int rbase = k0 - q0 + 960;
        // stage K (vector copies) and V^T hi/lo (vector load + scalar transpose writes)
        #pragma unroll
        for (int i = 0; i < 2; i++) {
            const int idx = tid + i * 256;
            const int r = idx >> 3, c8 = (idx & 7) * 8;
            *(uint4*)&Ks[r * 72 + c8] = *(const uint4*)&kg[kvbase + (size_t)r * DMODEL + c8];
            const f16x8 vh8 = *(const f16x8*)&vhg[kvbase + (size_t)r * DMODEL + c8];
            const f16x8 vl8 = *(const f16x8*)&vlg[kvbase + (size_t)r * DMODEL + c8];
            #pragma unroll
            for (int j = 0; j < 8; j++) {
                Vth[(c8 + j) * 72 + r] = vh8[j];
                Vtl[(c8 + j) * 72 + r] = vl8[j];
            }
        }
        __syncthreads();

        // S = Q K^T
        f32x4 S[4];
        #pragma unroll
        for (int t = 0; t < 4; t++) { S[t][0]=0.f; S[t][1]=0.f; S[t][2]=0.f; S[t][3]=0.f; }
        #pragma unroll
        for (int t = 0; t < 4; t++)
            #pragma unroll
            for (int s = 0; s < 2; s++) {
                const f16x8 kf = *(const f16x8*)&Ks[(16*t + c) * 72 + s*32 + quad*8];
                S[t] = MFMAH(qh[s], kf, S[t]);
            }
        // rel term: R = Qh.Eh + Qh.El ; R2 = Qm.Eh (recombined /1024)
        f32x4 R[5], R2[5];
        #pragma unroll
        for (int u = 0; u < 5; u++) {
            R[u][0]=0.f; R[u][1]=0.f; R[u][2]=0.f; R[u][3]=0.f;
            R2[u][0]=0.f; R2[u][1]=0.f; R2[u][2]=0.f; R2[u][3]=0.f;
        }
        #pragma unroll
        for (int u = 0; u < 5; u++) {
            int gr = rbase + Jb + 16 * u + c;
            gr = gr < 0 ? 0 : (gr > 2046 ? 2046 : gr);
            const size_t eb = (size_t)gr * HDIM;
            const f16x8 eh0 = *(const f16x8*)&Ehi[eb + quad * 8];
            const f16x8 eh1 = *(const f16x8*)&Ehi[eb + 32 + quad * 8];
            const f16x8 el0 = *(const f16x8*)&Elo[eb + quad * 8];
            const f16x8 el1 = *(const f16x8*)&Elo[eb + 32 + quad * 8];
            R[u]  = MFMAH(qh[0], eh0, R[u]);
            R[u]  = MFMAH(qh[1], eh1, R[u]);
            R[u]  = MFMAH(qh[0], el0, R[u]);
            R[u]  = MFMAH(qh[1], el1, R[u]);
            R2[u] = MFMAH(qm[0], eh0, R2[u]);
            R2[u] = MFMAH(qm[1], eh1, R2[u]);
        }
        #pragma unroll
        for (int u = 0; u < 5; u++)
            #pragma unroll
            for (int r = 0; r < 4; r++)
                R[u][r] = fmaf(R2[u][r], 9.765625e-4f, R[u][r]);
        // skew gather via bpermute: jj = kl - q + 15
        float bp[4][5];
        #pragma unroll
        for (int r = 0; r < 4; r++) {
            const int q = quad * 4 + r;
            const int srcl = (quad << 4) | ((c - q + 15) & 15);
            #pragma unroll
            for (int u = 0; u < 5; u++)
                bp[r][u] = __int_as_float(__builtin_amdgcn_ds_bpermute(srcl << 2, __float_as_int(R[u][r])));
        }
        float mkv[4];
        #pragma unroll
        for (int t = 0; t < 4; t++) mkv[t] = mkp[k0 + 16*t + c];
        float scv[4][4];
        float tmax[4] = {-3e38f, -3e38f, -3e38f, -3e38f};
        #pragma unroll
        for (int t = 0; t < 4; t++)
            #pragma unroll
            for (int r = 0; r < 4; r++) {
                const int q = quad*4 + r;
                const int jj = 16*t + c - q + 15;
                const float rv = ((jj >> 4) == t) ? bp[r][t] : bp[r][t+1];
                const float v = (S[t][r] + rv) * 0.125f + mkv[t];
                scv[t][r] = v;
                tmax[r] = fmaxf(tmax[r], v);
            }
        #pragma unroll
        for (int r = 0; r < 4; r++) {
            tmax[r] = fmaxf(tmax[r], __shfl_xor(tmax[r], 1));
            tmax[r] = fmaxf(tmax[r], __shfl_xor(tmax[r], 2));
            tmax[r] = fmaxf(tmax[r], __shfl_xor(tmax[r], 4));
            tmax[r] = fmaxf(tmax[r], __shfl_xor(tmax[r], 8));
        }
        float corr[4];
        #pragma unroll
        for (int r = 0; r < 4; r++) {
            const float mn = fmaxf(mrun[r], tmax[r]);
            corr[r] = __expf(mrun[r] - mn);
            mrun[r] = mn;
            lrun[r] *= corr[r];
        }
        #pragma unroll
        for (int dt = 0; dt < 4; dt++)
            #pragma unroll
            for (int r = 0; r < 4; r++) O[dt][r] *= corr[r];
        float psum[4] = {0.f, 0.f, 0.f, 0.f};
        #pragma unroll
        for (int t = 0; t < 4; t++)
            #pragma unroll
            for (int r = 0; r < 4; r++) {
                const float p = __expf(scv[t][r] - mrun[r]);
                psum[r] += p;
                const _Float16 hp = (_Float16)p;
                Phs[(w*16 + quad*4 + r)*72 + 16*t + c] = hp;
                Pls[(w*16 + quad*4 + r)*72 + 16*t + c] = (_Float16)(p - (float)hp);
            }
        #pragma unroll
        for (int r = 0; r < 4; r++) {
            psum[r] += __shfl_xor(psum[r], 1);
            psum[r] += __shfl_xor(psum[r], 2);
            psum[r] += __shfl_xor(psum[r], 4);
            psum[r] += __shfl_xor(psum[r], 8);
            lrun[r] += psum[r];
        }
        __syncthreads();  // Phs/Pls written by all waves before reads below; also guards Ks/Vt restage
        f16x8 pfh[2], pfl[2];
        #pragma unroll
        for (int s = 0; s < 2; s++) {
            pfh[s] = *(const f16x8*)&Phs[(w*16 + c)*72 + s*32 + quad*8];
            pfl[s] = *(const f16x8*)&Pls[(w*16 + c)*72 + s*32 + quad*8];
        }
        #pragma unroll
        for (int dt = 0; dt < 4; dt++)
            #pragma unroll
            for (int s = 0; s < 2; s++) {
                const f16x8 vhf = *(const f16x8*)&Vth[(16*dt + c)*72 + s*32 + quad*8];
                const f16x8 vlf = *(const f16x8*)&Vtl[(16*dt + c)*72 + s*32 + quad*8];
                O[dt] = MFMAH(pfh[s], vhf, O[dt]);
                O[dt] = MFMAH(pfl[s], vhf, O[dt]);
                O[dt] = MFMAH(pfh[s], vlf, O[dt]);
            }
        __syncthreads();
    }
    float inv[4];
    #pragma unroll
    for (int r = 0; r < 4; r++) inv[r] = 1.f / lrun[r];
    #pragma unroll
    for (int dt = 0; dt < 4; dt++)
        #pragma unroll
        for (int r = 0; r < 4; r++) {
            const float v = O[dt][r] * inv[r];
            const size_t oix = base + (size_t)(q0 + 16*w + quad*4 + r) * DMODEL + 16*dt + c;
            const unsigned hb = f2bf(v);
            obh[oix] = (unsigned short)hb;
            obl[oix] = (unsigned short)f2bf(v - bf2f(hb));
        }
}

extern "C" void kernel_launch(void* const* d_in, const int* in_sizes, int n_in,
                              void* d_out, int out_size, void* d_ws, size_t ws_size,
                              hipStream_t stream)
{
    const float* x       = (const float*)d_in[0];
    const float* mask_in = (const float*)d_in[1];
    const float* p_kf    = (const float*)d_in[2];
    const float* enc_w1  = (const float*)d_in[3];
    const float* enc_b1  = (const float*)d_in[4];
    const float* enc_a1  = (const float*)d_in[5];
    const float* enc_w2  = (const float*)d_in[6];
    const float* enc_b2  = (const float*)d_in[7];
    const float* enc_a2  = (const float*)d_in[8];
    const float* kf_w1   = (const float*)d_in[9];
    const float* kf_b1   = (const float*)d_in[10];
    const float* kf_a    = (const float*)d_in[11];
    const float* kf_w2   = (const float*)d_in[12];
    const float* kf_b2   = (const float*)d_in[13];
    const float* rel_w1  = (const float*)d_in[14];
    const float* rel_b1  = (const float*)d_in[15];
    const float* rel_a   = (const float*)d_in[16];
    const float* rel_w2  = (const float*)d_in[17];
    const float* rel_b2  = (const float*)d_in[18];
    const float* ln_g    = (const float*)d_in[19];
    const float* ln_b    = (const float*)d_in[20];
    const float* wq      = (const float*)d_in[21];
    const float* wk      = (const float*)d_in[22];
    const float* wv      = (const float*)d_in[23];
    const float* wo      = (const float*)d_in[24];
    const float* wob     = (const float*)d_in[25];
    const float* fw1     = (const float*)d_in[26];
    const float* fb1     = (const float*)d_in[27];
    const float* fa      = (const float*)d_in[28];
    const float* fw2     = (const float*)d_in[29];
    const float* fb2     = (const float*)d_in[30];
    const float* dw1     = (const float*)d_in[31];
    const float* db1     = (const float*)d_in[32];
    const float* da      = (const float*)d_in[33];
    const float* dw2     = (const float*)d_in[34];
    const float* db2     = (const float*)d_in[35];
    float* out = (float*)d_out;

    // ---- workspace layout (bytes), total ~76.5 MB ----
    char* p = (char*)d_ws;
    const size_t SZ_TD  = (size_t)NTOK * DMODEL;      // 2M elems
    float* h = (float*)p;                 p += SZ_TD * 4;
    unsigned short* hnh = (unsigned short*)p; p += SZ_TD * 2;
    unsigned short* hnl = (unsigned short*)p; p += SZ_TD * 2;
    unsigned short* qhg = (unsigned short*)p; p += SZ_TD * 2;
    unsigned short* qmg = (unsigned short*)p; p += SZ_TD * 2;
    unsigned short* kg  = (unsigned short*)p; p += SZ_TD * 2;
    unsigned short* vhg = (unsigned short*)p; p += SZ_TD * 2;
    unsigned short* vlg = (unsigned short*)p; p += SZ_TD * 2;
    unsigned short* obh = (unsigned short*)p; p += SZ_TD * 2;
    unsigned short* obl = (unsigned short*)p; p += SZ_TD * 2;
    unsigned short* midh = (unsigned short*)p; p += (size_t)NTOK * DFF * 2;
    unsigned short* midl = (unsigned short*)p; p += (size_t)NTOK * DFF * 2;
    unsigned short* Ehi = (unsigned short*)p; p += (size_t)2048 * HDIM * 2;
    unsigned short* Elo = (unsigned short*)p; p += (size_t)2048 * HDIM * 2;
    float* mk = (float*)p;
    float* pe = (float*)obh;   // 8 MB spanning obh+obl (free during encode)

    const dim3 blk256(256), blk64(64);
    const dim3 g512(512/64, NTOK/128);
    const dim3 g2048(2048/64, NTOK/128);
    const dim3 g256(256/64, NTOK/128);

    e_kernel<<<dim3(2047), blk64, 0, stream>>>(rel_w1, rel_b1, rel_a, rel_w2, rel_b2, Ehi, Elo);
    mask_kernel<<<dim3(NTOK), blk64, 0, stream>>>(mask_in, mk);
    // keyframe: kf1 -> (vhg,vlg) bf16 pair; kf2 -> pe fp32
    kf1_kernel<<<dim3(NTOK*DMODEL/256), blk256, 0, stream>>>(p_kf, kf_w1, kf_b1, kf_a, vhg, vlg);
    gemm_u<<<g512, blk256, 0, stream>>>(vhg, vlg, nullptr, nullptr, 0, 0, 0, kf_w2, kf_b2,
                                        nullptr, nullptr, pe, nullptr, nullptr, DMODEL, DMODEL, MODE_F32);
    // enc1 (fp32 concat A) -> mid pair; enc2 -> h fp32 (+pe res after prelu)
    gemm_u<<<g512, blk256, 0, stream>>>(nullptr, nullptr, x, mask_in, DMODEL, DMODEL, DMODEL,
                                        enc_w1, enc_b1, enc_a1, nullptr, nullptr, midh, midl,
                                        DMODEL, 2*DMODEL, MODE_BF);
    gemm_u<<<g512, blk256, 0, stream>>>(midh, midl, nullptr, nullptr, 0, 0, 0, enc_w2, enc_b2,
                                        enc_a2, pe, h, nullptr, nullptr, DMODEL, DMODEL, MODE_F32);

    for (int i = 0; i < NLAYER; i++) {
        const size_t wofs = (size_t)i * DMODEL * DMODEL;
        ln_kernel<<<dim3(NTOK), blk64, 0, stream>>>(h, ln_g, ln_b, hnh, hnl);
        gemm_u<<<g512, blk256, 0, stream>>>(hnh, hnl, nullptr, nullptr, 0, 0, 0, wq + wofs, nullptr,
                                            nullptr, nullptr, nullptr, qhg, qmg, DMODEL, DMODEL, MODE_F16Q);
        gemm_u<<<g512, blk256, 0, stream>>>(hnh, hnl, nullptr, nullptr, 0, 0, 0, wk + wofs, nullptr,
                                            nullptr, nullptr, nullptr, kg, nullptr, DMODEL, DMODEL, MODE_F16K);
        gemm_u<<<g512, blk256, 0, stream>>>(hnh, hnl, nullptr, nullptr, 0, 0, 0, wv + wofs, nullptr,
                                            nullptr, nullptr, nullptr, vhg, vlg, DMODEL, DMODEL, MODE_F16V);
        attn_mfma<<<dim3(TT/64, NHEAD, BB), blk256, 0, stream>>>(
            (const _Float16*)qhg, (const _Float16*)qmg, (const _Float16*)kg,
            (const _Float16*)vhg, (const _Float16*)vlg,
            (const _Float16*)Ehi, (const _Float16*)Elo, mk, obh, obl);
        gemm_u<<<g512, blk256, 0, stream>>>(obh, obl, nullptr, nullptr, 0, 0, 0, wo + wofs,
                                            wob + (size_t)i*DMODEL, nullptr, h, h, nullptr, nullptr,
                                            DMODEL, DMODEL, MODE_F32);
        ln_kernel<<<dim3(NTOK), blk64, 0, stream>>>(h, ln_g, ln_b, hnh, hnl);
        gemm_u<<<g2048, blk256, 0, stream>>>(hnh, hnl, nullptr, nullptr, 0, 0, 0,
                                             fw1 + (size_t)i*DMODEL*DFF, fb1 + (size_t)i*DFF,
                                             fa + i, nullptr, nullptr, midh, midl, DFF, DMODEL, MODE_BF);
        gemm_u<<<g512, blk256, 0, stream>>>(midh, midl, nullptr, nullptr, 0, 0, 0,
                                            fw2 + (size_t)i*DFF*DMODEL, fb2 + (size_t)i*DMODEL,
                                            nullptr, h, h, nullptr, nullptr, DMODEL, DFF, MODE_F32);
    }
    // decoder: h -> pair -> dec1 (prelu, pair) -> dec2 -> out
    cvt_pair<<<dim3(SZ_TD/1024), blk256, 0, stream>>>(h, hnh, hnl);
    gemm_u<<<g512, blk256, 0, stream>>>(hnh, hnl, nullptr, nullptr, 0, 0, 0, dw1, db1,
                                        da, nullptr, nullptr, midh, midl, DMODEL, DMODEL, MODE_BF);
    gemm_u<<<g256, blk256, 0, stream>>>(midh, midl, nullptr, nullptr, 0, 0, 0, dw2, db2,
                                        nullptr, nullptr, out, nullptr, nullptr, MFOUT, DMODEL, MODE_F32);
}